// Round 9
// baseline (175.590 us; speedup 1.0000x reference)
//
#include <hip/hip_runtime.h>
#include <hip/hip_bf16.h>

typedef __attribute__((ext_vector_type(8))) short short8;
typedef __attribute__((ext_vector_type(4))) float f32x4;
typedef unsigned short ushort_t;

__device__ __forceinline__ ushort_t f2bf(float f) {
    union { __hip_bfloat16 h; ushort_t u; } c;
    c.h = __float2bfloat16(f);
    return c.u;
}

__device__ __forceinline__ void gload16(const ushort_t* g, ushort_t* l) {
    __builtin_amdgcn_global_load_lds(
        (const __attribute__((address_space(1))) void*)g,
        (__attribute__((address_space(3))) void*)l, 16, 0, 0);
}

// ---------------- prep: z<3 transpose W_z fp32->bf16; z==3 convert x --------
__global__ __launch_bounds__(256) void k_prep(const float* __restrict__ x,
                                              const float* __restrict__ W0,
                                              const float* __restrict__ W1,
                                              const float* __restrict__ W2,
                                              ushort_t* __restrict__ xb,
                                              ushort_t* __restrict__ Wt) {
    const int bz = blockIdx.z;
    if (bz == 3) {
        // convert x fp32 -> bf16: 1024 blocks x 256 thr x 8 elems x 4 passes
        const int t = threadIdx.y * 32 + threadIdx.x;
        size_t base = ((size_t)(blockIdx.y * 32 + blockIdx.x) * 256 + t) * 8;
#pragma unroll
        for (int p = 0; p < 4; ++p) {
            size_t idx = base + (size_t)p * 2097152;
            float4 a = *(const float4*)(x + idx);
            float4 b = *(const float4*)(x + idx + 4);
            short8 o;
            o[0] = (short)f2bf(a.x); o[1] = (short)f2bf(a.y);
            o[2] = (short)f2bf(a.z); o[3] = (short)f2bf(a.w);
            o[4] = (short)f2bf(b.x); o[5] = (short)f2bf(b.y);
            o[6] = (short)f2bf(b.z); o[7] = (short)f2bf(b.w);
            *(short8*)(xb + idx) = o;
        }
        return;
    }
    const float* W = (bz == 0) ? W0 : (bz == 1) ? W1 : W2;
    ushort_t* out = Wt + (size_t)bz * 1024 * 1024;
    __shared__ float tile[32][33];
    int tx = threadIdx.x, ty = threadIdx.y;            // 32 x 8
    int d0 = blockIdx.y * 32, e0 = blockIdx.x * 32;
#pragma unroll
    for (int i = 0; i < 32; i += 8)
        tile[ty + i][tx] = W[(size_t)(d0 + ty + i) * 1024 + e0 + tx];
    __syncthreads();
#pragma unroll
    for (int i = 0; i < 32; i += 8)
        out[(size_t)(e0 + ty + i) * 1024 + d0 + tx] = f2bf(tile[tx][ty + i]);
}

// ---------------- GEMM (m97 128x128): C = A * B^T ----------------
// All modes use XCD-chunked bijective block swizzle (T1, m204):
//   swz = (gid%8)*(nwg/8) + gid/8   (nwg % 8 == 0 in all three launches)
// MODE 0: proj  A=xb[8192][1024]  B=Wt[z][1024][1024]; z<2 -> QKV bf16;
//               z==2 -> V tile transposed via LDS bounce -> Vt[b][e][j]
// MODE 1: qk    triangular 544; writes P' = exp(s/32) bf16, causal-masked 0
// MODE 2: pv    A=P' lda=2048; B=Vt; rowsum via ones-MFMA; out = acc/rs
template <int MODE>
__global__ __launch_bounds__(256) void k_gemm(const ushort_t* __restrict__ Abase,
                                              const ushort_t* __restrict__ Bbase,
                                              void* __restrict__ Cbase,
                                              ushort_t* __restrict__ Vt) {
    int bm, bn, bz;
    const ushort_t* A;
    const ushort_t* B;
    int lda, ldb, nk;
    if constexpr (MODE == 0) {
        const int gid = blockIdx.x + 64 * blockIdx.y + 512 * blockIdx.z;
        const int swz = (gid & 7) * 192 + (gid >> 3);     // nwg=1536
        bm = swz & 63; bn = (swz >> 6) & 7; bz = swz >> 9;
        A = Abase; lda = 1024;
        B = Bbase + (size_t)bz * 1024 * 1024; ldb = 1024;
        nk = 32;
    } else if constexpr (MODE == 1) {
        const int gid = blockIdx.x + 136 * blockIdx.z;
        const int swz = (gid & 7) * 68 + (gid >> 3);      // nwg=544
        bz = swz / 136;
        const int xi = swz - bz * 136;
        bm = (int)((sqrtf(8.f * xi + 1.f) - 1.f) * 0.5f);
        while ((bm + 1) * (bm + 2) / 2 <= xi) ++bm;
        while (bm * (bm + 1) / 2 > xi) --bm;
        bn = xi - bm * (bm + 1) / 2;
        A = Abase + (size_t)bz * 2048 * 1024; lda = 1024;
        B = Bbase + (size_t)bz * 2048 * 1024; ldb = 1024;
        nk = 32;
    } else {
        const int gid = blockIdx.x + 16 * blockIdx.y + 128 * blockIdx.z;
        const int swz = (gid & 7) * 64 + (gid >> 3);      // nwg=512
        const int xr = swz & 15;                          // heavy/light interleave
        bm = (xr & 1) ? (15 - (xr >> 1)) : (xr >> 1);
        bn = (swz >> 4) & 7;
        bz = swz >> 7;
        A = Abase + (size_t)bz * 2048 * 2048; lda = 2048;
        B = Bbase + (size_t)bz * 1024 * 2048; ldb = 2048;
        nk = (bm + 1) * 4;  // causal K truncation: j <= bm*128+127
    }

    // MODE 0 reuses smem post-loop as a [128][130] transpose bounce (33.3KB)
    constexpr int SMEM_ELEMS = (MODE == 0) ? (128 * 130) : 8192;
    __shared__ ushort_t smem[SMEM_ELEMS];
    ushort_t* As = smem;          // [128][32] linear (gload_lds dest)
    ushort_t* Bs = smem + 4096;

    const int tid = threadIdx.x;
    const int l = tid & 63, wid = tid >> 6;
    const int wr = (wid >> 1) * 64, wc = (wid & 1) * 64;
    const int lr = l & 15, kc = (l >> 4) * 8;

    const int srow = tid >> 2, skb = (tid & 3) * 8;
    const ushort_t* ag = A + (size_t)(bm * 128 + srow) * lda + skb;
    const ushort_t* bg = B + (size_t)(bn * 128 + srow) * ldb + skb;
    const size_t a64 = (size_t)64 * lda, b64 = (size_t)64 * ldb;
    ushort_t* al = As + tid * 8;
    ushort_t* bl = Bs + tid * 8;

    f32x4 zero = {0.f, 0.f, 0.f, 0.f};
    f32x4 acc[4][4];
#pragma unroll
    for (int m = 0; m < 4; ++m)
#pragma unroll
        for (int n = 0; n < 4; ++n) acc[m][n] = zero;

    f32x4 rs[4];            // MODE 2 rowsums
    short8 ones;
#pragma unroll
    for (int e = 0; e < 8; ++e) ones[e] = (short)0x3F80;   // bf16 1.0
#pragma unroll
    for (int m = 0; m < 4; ++m) rs[m] = zero;

    for (int ks = 0; ks < nk; ++ks) {
        __syncthreads();
        gload16(ag, al);
        gload16(ag + a64, al + 2048);
        gload16(bg, bl);
        gload16(bg + b64, bl + 2048);
        ag += 32; bg += 32;
        __syncthreads();

        short8 a[4], b[4];
#pragma unroll
        for (int m = 0; m < 4; ++m)
            a[m] = *(const short8*)&As[(wr + m * 16 + lr) * 32 + kc];
#pragma unroll
        for (int n = 0; n < 4; ++n)
            b[n] = *(const short8*)&Bs[(wc + n * 16 + lr) * 32 + kc];
#pragma unroll
        for (int m = 0; m < 4; ++m)
#pragma unroll
            for (int n = 0; n < 4; ++n)
                acc[m][n] = __builtin_amdgcn_mfma_f32_16x16x32_bf16(a[m], b[n], acc[m][n], 0, 0, 0);
        if constexpr (MODE == 2) {
#pragma unroll
            for (int m = 0; m < 4; ++m)
                rs[m] = __builtin_amdgcn_mfma_f32_16x16x32_bf16(a[m], ones, rs[m], 0, 0, 0);
        }
    }

    const int rbase = (l >> 4) * 4;
    const int cbase = l & 15;

    if constexpr (MODE == 0) {
        if (bz == 2) {
            // V tile: transpose via LDS, write Vt[b][e][j] (b=batch, j=seq)
            __syncthreads();
#pragma unroll
            for (int m = 0; m < 4; ++m)
#pragma unroll
                for (int n = 0; n < 4; ++n) {
                    int col = wc + n * 16 + cbase;
                    int row0 = wr + m * 16 + rbase;
#pragma unroll
                    for (int r = 0; r < 4; ++r)
                        smem[col * 130 + row0 + r] = f2bf(acc[m][n][r]);
                }
            __syncthreads();
            const int e = tid >> 1, jh = (tid & 1) * 64;
            const int b = bm >> 4, j0 = (bm * 128) & 2047;
            ushort_t* dst = Vt + (size_t)b * 2097152 +
                            (size_t)(bn * 128 + e) * 2048 + j0 + jh;
            const ushort_t* src = smem + e * 130 + jh;
#pragma unroll
            for (int c = 0; c < 8; ++c)
                *(short8*)(dst + c * 8) = *(const short8*)(src + c * 8);
            return;
        }
    }

    float inv[4][4];
    if constexpr (MODE == 2) {
#pragma unroll
        for (int m = 0; m < 4; ++m)
#pragma unroll
            for (int r = 0; r < 4; ++r) inv[m][r] = 1.0f / rs[m][r];
    }

#pragma unroll
    for (int m = 0; m < 4; ++m) {
#pragma unroll
        for (int n = 0; n < 4; ++n) {
            int row0 = wr + m * 16 + rbase;
            int col = wc + n * 16 + cbase;
            int gcol = bn * 128 + col;
#pragma unroll
            for (int r = 0; r < 4; ++r) {
                int grow = bm * 128 + row0 + r;
                float v = acc[m][n][r];
                if constexpr (MODE == 0) {
                    ushort_t* C = (ushort_t*)Cbase + (size_t)bz * 8192 * 1024;
                    C[(size_t)grow * 1024 + gcol] = f2bf(v);
                } else if constexpr (MODE == 1) {
                    ushort_t* C = (ushort_t*)Cbase + (size_t)bz * 2048 * 2048;
                    // max-free softmax numerator: exp(s/32), causal mask -> 0
                    ushort_t pv = (gcol <= grow) ? f2bf(__expf(v * 0.03125f))
                                                 : (ushort_t)0;
                    C[(size_t)grow * 2048 + gcol] = pv;
                } else {
                    float* C = (float*)Cbase + (size_t)bz * 2048 * 1024;
                    C[(size_t)grow * 1024 + gcol] = v * inv[m][r];
                }
            }
        }
    }
}

extern "C" void kernel_launch(void* const* d_in, const int* in_sizes, int n_in,
                              void* d_out, int out_size, void* d_ws, size_t ws_size,
                              hipStream_t stream) {
    const float* x  = (const float*)d_in[0];
    const float* Wq = (const float*)d_in[1];
    const float* Wk = (const float*)d_in[2];
    const float* Wv = (const float*)d_in[3];

    char* ws = (char*)d_ws;
    ushort_t* xb     = (ushort_t*)(ws);                 // 16 MB
    ushort_t* Wt     = (ushort_t*)(ws + 16777216);      // 6 MB  [3][1024][1024]
    ushort_t* QKV    = (ushort_t*)(ws + 23068672);      // 48 MB [3][8192][1024] (z=2 slot unused)
    ushort_t* Vt     = (ushort_t*)(ws + 73400320);      // 16 MB [4][1024][2048]
    ushort_t* P      = (ushort_t*)(ws + 90177536);      // 32 MB [4][2048][2048] bf16

    ushort_t* Q = QKV;
    ushort_t* K = QKV + (size_t)8192 * 1024;

    k_prep<<<dim3(32, 32, 4), dim3(32, 8), 0, stream>>>(x, Wq, Wk, Wv, xb, Wt);
    k_gemm<0><<<dim3(64, 8, 3), 256, 0, stream>>>(xb, Wt, QKV, Vt);
    k_gemm<1><<<dim3(136, 1, 4), 256, 0, stream>>>(Q, K, P, nullptr);
    k_gemm<2><<<dim3(16, 8, 4), 256, 0, stream>>>(P, Vt, (float*)d_out, nullptr);
}